// Round 4
// baseline (899.107 us; speedup 1.0000x reference)
//
#include <hip/hip_runtime.h>

#define NBATCH 256
#define P 1024
#define Q 128
#define NS_LOOP 10

typedef _Float16 half8 __attribute__((ext_vector_type(8)));
typedef float f32x4 __attribute__((ext_vector_type(4)));
struct Half4 { _Float16 x, y, z, w; };   // 8 bytes

// Swizzled fp16 storage for 128x128 symmetric matrices:
// element (r,c) lives in Half4 slot  r*32 + ((c>>2) ^ (r&15)), component c&3.
__device__ __forceinline__ half8 frag_ld(const Half4* S, int rowbase, int slotbase, int lane) {
    const int r = rowbase + (lane & 15);
    const int g = (lane >> 4);
    const int rx = r & 15;
    const Half4 h1 = S[r * 32 + ((slotbase + g) ^ rx)];
    const Half4 h2 = S[r * 32 + ((slotbase + g + 4) ^ rx)];
    half8 v;
    v[0] = h1.x; v[1] = h1.y; v[2] = h1.z; v[3] = h1.w;
    v[4] = h2.x; v[5] = h2.y; v[6] = h2.z; v[7] = h2.w;
    return v;
}

// C-fragment position, stored TRANSPOSED (ok: iterates symmetric to O(eps)).
__device__ __forceinline__ int cpos(int RB, int CB, int lane) {
    const int r = CB + (lane & 15);
    const int s = (RB >> 2) + (lane >> 4);
    return r * 32 + (s ^ (r & 15));
}

__device__ __forceinline__ f32x4 cread(const Half4* S, int p) {
    const Half4 h = S[p];
    f32x4 v;
    v[0] = (float)h.x; v[1] = (float)h.y; v[2] = (float)h.z; v[3] = (float)h.w;
    return v;
}

__device__ __forceinline__ void cwrite(Half4* S, int p, f32x4 v) {
    Half4 h;
    h.x = (_Float16)v[0]; h.y = (_Float16)v[1]; h.z = (_Float16)v[2]; h.w = (_Float16)v[3];
    S[p] = h;
}

// ---------------------------------------------------------------------------
// Kernel 1 (fused): gram (fp32 VALU) + Newton-Schulz inverse-sqrt (fp16 MFMA).
// Writes raw gram (fp32) AND Zg[n] ~= gram^{-1/2} (fp32, fp16-accurate).
// ---------------------------------------------------------------------------
__global__ __launch_bounds__(512) void gram_ns_kernel(
    const float* __restrict__ X, const float* __restrict__ G,
    const float* __restrict__ lrp, float* __restrict__ gram,
    float* __restrict__ Zg)
{
    __shared__ __align__(16) unsigned char pool[98304];
    Half4* sW = (Half4*)pool;
    Half4* sZ = (Half4*)(pool + 32768);
    Half4* sM = (Half4*)(pool + 65536);
    float* sT = (float*)(pool + 65536);   // gram staging aliases sM (16KB)
    __shared__ float sRed[8];

    const int n = blockIdx.x;
    const int tid = threadIdx.x;
    const float lr = *lrp;
    const float* xb = X + (size_t)n * P * Q;
    const float* gb = G + (size_t)n * P * Q;

    // ================= gram phase: acc = temp^T temp =================
    const int ty = tid >> 5, tx = tid & 31;   // 16 x 32 grid, 8x4 tiles
    float acc[8][4];
#pragma unroll
    for (int i = 0; i < 8; ++i)
#pragma unroll
        for (int j = 0; j < 4; ++j) acc[i][j] = 0.0f;

    float4 xA[2], gA[2], xB[2], gB[2];
#pragma unroll
    for (int t = 0; t < 2; ++t) {
        const int idx = tid + t * 512;
        xA[t] = ((const float4*)xb)[idx];
        gA[t] = ((const float4*)gb)[idx];
    }

    for (int c = 0; c < 32; c += 2) {
        __syncthreads();
#pragma unroll
        for (int t = 0; t < 2; ++t) {
            const int idx = tid + t * 512;
            float4 tv;
            tv.x = xA[t].x - lr * gA[t].x; tv.y = xA[t].y - lr * gA[t].y;
            tv.z = xA[t].z - lr * gA[t].z; tv.w = xA[t].w - lr * gA[t].w;
            ((float4*)sT)[idx] = tv;
        }
        {
            const float4* xc = (const float4*)(xb + (size_t)(c + 1) * 32 * Q);
            const float4* gc = (const float4*)(gb + (size_t)(c + 1) * 32 * Q);
#pragma unroll
            for (int t = 0; t < 2; ++t) {
                const int idx = tid + t * 512;
                xB[t] = xc[idx]; gB[t] = gc[idx];
            }
        }
        __syncthreads();
        for (int p = 0; p < 32; ++p) {
            float a[8];
#pragma unroll
            for (int i = 0; i < 8; ++i) a[i] = sT[p * 128 + ty * 8 + i];
            const float4 bv = ((const float4*)(sT + p * 128))[tx];
            const float b[4] = {bv.x, bv.y, bv.z, bv.w};
#pragma unroll
            for (int i = 0; i < 8; ++i)
#pragma unroll
                for (int j = 0; j < 4; ++j) acc[i][j] += a[i] * b[j];
        }
        __syncthreads();
#pragma unroll
        for (int t = 0; t < 2; ++t) {
            const int idx = tid + t * 512;
            float4 tv;
            tv.x = xB[t].x - lr * gB[t].x; tv.y = xB[t].y - lr * gB[t].y;
            tv.z = xB[t].z - lr * gB[t].z; tv.w = xB[t].w - lr * gB[t].w;
            ((float4*)sT)[idx] = tv;
        }
        if (c + 2 < 32) {
            const float4* xc = (const float4*)(xb + (size_t)(c + 2) * 32 * Q);
            const float4* gc = (const float4*)(gb + (size_t)(c + 2) * 32 * Q);
#pragma unroll
            for (int t = 0; t < 2; ++t) {
                const int idx = tid + t * 512;
                xA[t] = xc[idx]; gA[t] = gc[idx];
            }
        }
        __syncthreads();
        for (int p = 0; p < 32; ++p) {
            float a[8];
#pragma unroll
            for (int i = 0; i < 8; ++i) a[i] = sT[p * 128 + ty * 8 + i];
            const float4 bv = ((const float4*)(sT + p * 128))[tx];
            const float b[4] = {bv.x, bv.y, bv.z, bv.w};
#pragma unroll
            for (int i = 0; i < 8; ++i)
#pragma unroll
                for (int j = 0; j < 4; ++j) acc[i][j] += a[i] * b[j];
        }
    }

    // ---- write raw gram (fp32) for the refiner ----
    float* gmo = gram + (size_t)n * Q * Q;
#pragma unroll
    for (int i = 0; i < 8; ++i) {
        float4 v = make_float4(acc[i][0], acc[i][1], acc[i][2], acc[i][3]);
        ((float4*)(gmo + (size_t)(ty * 8 + i) * Q))[tx] = v;
    }

    // ---- Frobenius norm ----
    float ss = 0.0f;
#pragma unroll
    for (int i = 0; i < 8; ++i)
#pragma unroll
        for (int j = 0; j < 4; ++j) ss += acc[i][j] * acc[i][j];
#pragma unroll
    for (int off = 32; off > 0; off >>= 1) ss += __shfl_down(ss, off, 64);
    if ((tid & 63) == 0) sRed[tid >> 6] = ss;
    __syncthreads();
    float csum = 0.0f;
#pragma unroll
    for (int w = 0; w < 8; ++w) csum += sRed[w];
    const float c = sqrtf(csum);
    const float rc = 1.0f / c;

    // ---- init: W0 = gram/c (fp16), Z0 = 1.5I - 0.5*W0 ----
#pragma unroll
    for (int i = 0; i < 8; ++i) {
        const int row = ty * 8 + i;
        const int slot = row * 32 + (tx ^ (row & 15));
        float wv[4], zv[4];
#pragma unroll
        for (int j = 0; j < 4; ++j) {
            wv[j] = acc[i][j] * rc;
            zv[j] = -0.5f * wv[j] + (((row >> 2) == tx && (row & 3) == j) ? 1.5f : 0.0f);
        }
        Half4 wh, zh;
        wh.x = (_Float16)wv[0]; wh.y = (_Float16)wv[1]; wh.z = (_Float16)wv[2]; wh.w = (_Float16)wv[3];
        zh.x = (_Float16)zv[0]; zh.y = (_Float16)zv[1]; zh.z = (_Float16)zv[2]; zh.w = (_Float16)zv[3];
        sW[slot] = wh;
        sZ[slot] = zh;
    }
    __syncthreads();

    // ================= NS phase (fp16 MFMA) =================
    const int lane = tid & 63;
    const int wid = tid >> 6;
    const int wr = wid >> 2;
    const int wc = wid & 3;
    const f32x4 zero4 = {0.0f, 0.0f, 0.0f, 0.0f};

    for (int it = 0; it < NS_LOOP; ++it) {
        // --- GEMM1: M = 1.5W - 0.5*(W*W) ---
        f32x4 a1[4][2];
#pragma unroll
        for (int fi = 0; fi < 4; ++fi)
#pragma unroll
            for (int fj = 0; fj < 2; ++fj) a1[fi][fj] = zero4;
#pragma unroll
        for (int kb = 0; kb < 4; ++kb) {
            half8 af[4], bf[2];
#pragma unroll
            for (int fi = 0; fi < 4; ++fi) af[fi] = frag_ld(sW, wr * 64 + fi * 16, kb * 8, lane);
#pragma unroll
            for (int fj = 0; fj < 2; ++fj) bf[fj] = frag_ld(sW, wc * 32 + fj * 16, kb * 8, lane);
#pragma unroll
            for (int fi = 0; fi < 4; ++fi)
#pragma unroll
                for (int fj = 0; fj < 2; ++fj)
                    a1[fi][fj] = __builtin_amdgcn_mfma_f32_16x16x32_f16(af[fi], bf[fj], a1[fi][fj], 0, 0, 0);
        }
#pragma unroll
        for (int fi = 0; fi < 4; ++fi)
#pragma unroll
            for (int fj = 0; fj < 2; ++fj) {
                const int p = cpos(wr * 64 + fi * 16, wc * 32 + fj * 16, lane);
                cwrite(sM, p, 1.5f * cread(sW, p) - 0.5f * a1[fi][fj]);
            }
        __syncthreads();

        // --- GEMM2: Wnew = 1.5M - 0.5*(M*W) ---
        f32x4 a2[4][2];
#pragma unroll
        for (int fi = 0; fi < 4; ++fi)
#pragma unroll
            for (int fj = 0; fj < 2; ++fj) a2[fi][fj] = zero4;
#pragma unroll
        for (int kb = 0; kb < 4; ++kb) {
            half8 af[4], bf[2];
#pragma unroll
            for (int fi = 0; fi < 4; ++fi) af[fi] = frag_ld(sM, wr * 64 + fi * 16, kb * 8, lane);
#pragma unroll
            for (int fj = 0; fj < 2; ++fj) bf[fj] = frag_ld(sW, wc * 32 + fj * 16, kb * 8, lane);
#pragma unroll
            for (int fi = 0; fi < 4; ++fi)
#pragma unroll
                for (int fj = 0; fj < 2; ++fj)
                    a2[fi][fj] = __builtin_amdgcn_mfma_f32_16x16x32_f16(af[fi], bf[fj], a2[fi][fj], 0, 0, 0);
        }
        f32x4 wn[4][2];
#pragma unroll
        for (int fi = 0; fi < 4; ++fi)
#pragma unroll
            for (int fj = 0; fj < 2; ++fj) {
                const int p = cpos(wr * 64 + fi * 16, wc * 32 + fj * 16, lane);
                wn[fi][fj] = 1.5f * cread(sM, p) - 0.5f * a2[fi][fj];
            }
        __syncthreads();
#pragma unroll
        for (int fi = 0; fi < 4; ++fi)
#pragma unroll
            for (int fj = 0; fj < 2; ++fj)
                cwrite(sW, cpos(wr * 64 + fi * 16, wc * 32 + fj * 16, lane), wn[fi][fj]);
        __syncthreads();

        // --- GEMM3: Znew = 1.5Z - 0.5*(Wnew*Z) ---
        f32x4 a3[4][2];
#pragma unroll
        for (int fi = 0; fi < 4; ++fi)
#pragma unroll
            for (int fj = 0; fj < 2; ++fj) a3[fi][fj] = zero4;
#pragma unroll
        for (int kb = 0; kb < 4; ++kb) {
            half8 af[4], bf[2];
#pragma unroll
            for (int fi = 0; fi < 4; ++fi) af[fi] = frag_ld(sW, wr * 64 + fi * 16, kb * 8, lane);
#pragma unroll
            for (int fj = 0; fj < 2; ++fj) bf[fj] = frag_ld(sZ, wc * 32 + fj * 16, kb * 8, lane);
#pragma unroll
            for (int fi = 0; fi < 4; ++fi)
#pragma unroll
                for (int fj = 0; fj < 2; ++fj)
                    a3[fi][fj] = __builtin_amdgcn_mfma_f32_16x16x32_f16(af[fi], bf[fj], a3[fi][fj], 0, 0, 0);
        }
        f32x4 zn[4][2];
#pragma unroll
        for (int fi = 0; fi < 4; ++fi)
#pragma unroll
            for (int fj = 0; fj < 2; ++fj) {
                const int p = cpos(wr * 64 + fi * 16, wc * 32 + fj * 16, lane);
                zn[fi][fj] = 1.5f * cread(sZ, p) - 0.5f * a3[fi][fj];
            }
        __syncthreads();
#pragma unroll
        for (int fi = 0; fi < 4; ++fi)
#pragma unroll
            for (int fj = 0; fj < 2; ++fj)
                cwrite(sZ, cpos(wr * 64 + fi * 16, wc * 32 + fj * 16, lane), zn[fi][fj]);
        __syncthreads();
    }

    // ---- Zg = Z / sqrt(c) ----
    const float rs = 1.0f / sqrtf(c);
    float* zo = Zg + (size_t)n * Q * Q;
#pragma unroll
    for (int t = 0; t < 8; ++t) {
        const int idx = tid + t * 512;
        const int row = idx >> 5, c4 = idx & 31;
        const Half4 h = sZ[row * 32 + (c4 ^ (row & 15))];
        float4 o;
        o.x = (float)h.x * rs; o.y = (float)h.y * rs;
        o.z = (float)h.z * rs; o.w = (float)h.w * rs;
        ((float4*)(zo + row * Q))[c4] = o;
    }
}

// ---------------------------------------------------------------------------
// Kernel 1b: one fp32 Newton-Schulz refinement step (quadratic cleanup).
//   Z = 1.5*Y - 0.5 * Y*(S*(Y*Y))   with EXACT operand order (no commuting:
// fp16 noise breaks commutativity at the 1e-3 level). Associativity used:
//   U = Y*Y; per 32-row chunk: R = Y[rows]*S (S streamed from global, L2-hot),
//   D = R*U, Znew_rows = 1.5*Y_rows - 0.5*D -> overwrite Zg.
// LDS: sY 64K + sU 64K + sR 16K = 144K.
// ---------------------------------------------------------------------------
__global__ __launch_bounds__(512) void refine_kernel(
    const float* __restrict__ gram, float* __restrict__ Zg)
{
    __shared__ float sY[Q * Q];
    __shared__ float sU[Q * Q];
    __shared__ float sR[32 * Q];
    const int n = blockIdx.x;
    const int tid = threadIdx.x;
    const float* gm = gram + (size_t)n * Q * Q;
    float* zg = Zg + (size_t)n * Q * Q;
    const int ty = tid >> 5, tx = tid & 31;

    // load Y
#pragma unroll
    for (int t = 0; t < 8; ++t) {
        const int idx = tid + t * 512;
        ((float4*)sY)[idx] = ((const float4*)zg)[idx];
    }
    __syncthreads();

    // U = Y*Y  (true orientation: U_ij = sum_k Y[i][k] Y[k][j])
    {
        float acc[8][4];
#pragma unroll
        for (int i = 0; i < 8; ++i)
#pragma unroll
            for (int j = 0; j < 4; ++j) acc[i][j] = 0.0f;
        for (int k = 0; k < Q; ++k) {
            float a[8];
#pragma unroll
            for (int i = 0; i < 8; ++i) a[i] = sY[(ty * 8 + i) * Q + k];
            const float4 bv = ((const float4*)(sY + k * Q))[tx];
            const float b[4] = {bv.x, bv.y, bv.z, bv.w};
#pragma unroll
            for (int i = 0; i < 8; ++i)
#pragma unroll
                for (int j = 0; j < 4; ++j) acc[i][j] += a[i] * b[j];
        }
#pragma unroll
        for (int i = 0; i < 8; ++i) {
            float4 v = make_float4(acc[i][0], acc[i][1], acc[i][2], acc[i][3]);
            ((float4*)(sU + (ty * 8 + i) * Q))[tx] = v;
        }
    }
    __syncthreads();

    // per-chunk: R = Y[rows]*S ; D = R*U ; Z = 1.5Y - 0.5D
    for (int ch = 0; ch < 4; ++ch) {
        const int r0 = ch * 32 + ty * 2;
        float acc[2][4];
#pragma unroll
        for (int i = 0; i < 2; ++i)
#pragma unroll
            for (int j = 0; j < 4; ++j) acc[i][j] = 0.0f;
        for (int k = 0; k < Q; ++k) {
            const float a0 = sY[(r0 + 0) * Q + k];
            const float a1 = sY[(r0 + 1) * Q + k];
            const float4 bv = ((const float4*)(gm + (size_t)k * Q))[tx];
            acc[0][0] += a0 * bv.x; acc[0][1] += a0 * bv.y;
            acc[0][2] += a0 * bv.z; acc[0][3] += a0 * bv.w;
            acc[1][0] += a1 * bv.x; acc[1][1] += a1 * bv.y;
            acc[1][2] += a1 * bv.z; acc[1][3] += a1 * bv.w;
        }
        __syncthreads();  // prev chunk's sR readers done
#pragma unroll
        for (int i = 0; i < 2; ++i) {
            float4 v = make_float4(acc[i][0], acc[i][1], acc[i][2], acc[i][3]);
            ((float4*)(sR + (ty * 2 + i) * Q))[tx] = v;
        }
        __syncthreads();

        float acc2[2][4];
#pragma unroll
        for (int i = 0; i < 2; ++i)
#pragma unroll
            for (int j = 0; j < 4; ++j) acc2[i][j] = 0.0f;
        for (int k = 0; k < Q; ++k) {
            const float a0 = sR[(ty * 2 + 0) * Q + k];
            const float a1 = sR[(ty * 2 + 1) * Q + k];
            const float4 bv = ((const float4*)(sU + k * Q))[tx];
            acc2[0][0] += a0 * bv.x; acc2[0][1] += a0 * bv.y;
            acc2[0][2] += a0 * bv.z; acc2[0][3] += a0 * bv.w;
            acc2[1][0] += a1 * bv.x; acc2[1][1] += a1 * bv.y;
            acc2[1][2] += a1 * bv.z; acc2[1][3] += a1 * bv.w;
        }
#pragma unroll
        for (int i = 0; i < 2; ++i) {
            const float4 yv = ((const float4*)(sY + (r0 + i) * Q))[tx];
            float4 o;
            o.x = 1.5f * yv.x - 0.5f * acc2[i][0];
            o.y = 1.5f * yv.y - 0.5f * acc2[i][1];
            o.z = 1.5f * yv.z - 0.5f * acc2[i][2];
            o.w = 1.5f * yv.w - 0.5f * acc2[i][3];
            ((float4*)(zg + (size_t)(r0 + i) * Q))[tx] = o;
        }
    }
}

// ---------------------------------------------------------------------------
// Kernel 2: out[n] = temp[n] @ Zg[n]. 2 blocks/batch, 512 threads.
// ---------------------------------------------------------------------------
__global__ __launch_bounds__(512) void apply_kernel(
    const float* __restrict__ X, const float* __restrict__ G,
    const float* __restrict__ lrp, const float* __restrict__ Zg,
    float* __restrict__ out)
{
    __shared__ float sZf[Q * Q];
    __shared__ float sT2[128 * Q];

    const int n = blockIdx.x >> 1;
    const int rb = (blockIdx.x & 1) * 512;
    const int tid = threadIdx.x;
    const float lr = *lrp;
    const float* xb = X + (size_t)n * P * Q + (size_t)rb * Q;
    const float* gb = G + (size_t)n * P * Q + (size_t)rb * Q;
    float* ob = out + (size_t)n * P * Q + (size_t)rb * Q;

#pragma unroll
    for (int t = 0; t < 8; ++t) {
        const int idx = tid + t * 512;
        ((float4*)sZf)[idx] = ((const float4*)(Zg + (size_t)n * Q * Q))[idx];
    }

    const int ty = tid >> 5, tx = tid & 31;
    float4 xA[8], gA[8], xB[8], gB[8];
#pragma unroll
    for (int t = 0; t < 8; ++t) {
        const int idx = tid + t * 512;
        xA[t] = ((const float4*)xb)[idx];
        gA[t] = ((const float4*)gb)[idx];
    }

    for (int ch = 0; ch < 4; ch += 2) {
        __syncthreads();
#pragma unroll
        for (int t = 0; t < 8; ++t) {
            const int idx = tid + t * 512;
            float4 tv;
            tv.x = xA[t].x - lr * gA[t].x; tv.y = xA[t].y - lr * gA[t].y;
            tv.z = xA[t].z - lr * gA[t].z; tv.w = xA[t].w - lr * gA[t].w;
            ((float4*)sT2)[idx] = tv;
        }
        {
            const float4* xc = (const float4*)(xb + (size_t)(ch + 1) * 128 * Q);
            const float4* gc = (const float4*)(gb + (size_t)(ch + 1) * 128 * Q);
#pragma unroll
            for (int t = 0; t < 8; ++t) {
                const int idx = tid + t * 512;
                xB[t] = xc[idx]; gB[t] = gc[idx];
            }
        }
        __syncthreads();
        {
            float acc[8][4];
#pragma unroll
            for (int i = 0; i < 8; ++i)
#pragma unroll
                for (int j = 0; j < 4; ++j) acc[i][j] = 0.0f;
            for (int k = 0; k < Q; ++k) {
                float a[8];
#pragma unroll
                for (int i = 0; i < 8; ++i) a[i] = sT2[(ty * 8 + i) * 128 + k];
                const float4 bv = ((const float4*)(sZf + k * Q))[tx];
                const float b[4] = {bv.x, bv.y, bv.z, bv.w};
#pragma unroll
                for (int i = 0; i < 8; ++i)
#pragma unroll
                    for (int j = 0; j < 4; ++j) acc[i][j] += a[i] * b[j];
            }
            float* oc = ob + (size_t)ch * 128 * Q;
#pragma unroll
            for (int i = 0; i < 8; ++i) {
                float4 v = make_float4(acc[i][0], acc[i][1], acc[i][2], acc[i][3]);
                ((float4*)(oc + (size_t)(ty * 8 + i) * Q))[tx] = v;
            }
        }
        __syncthreads();
#pragma unroll
        for (int t = 0; t < 8; ++t) {
            const int idx = tid + t * 512;
            float4 tv;
            tv.x = xB[t].x - lr * gB[t].x; tv.y = xB[t].y - lr * gB[t].y;
            tv.z = xB[t].z - lr * gB[t].z; tv.w = xB[t].w - lr * gB[t].w;
            ((float4*)sT2)[idx] = tv;
        }
        if (ch + 2 < 4) {
            const float4* xc = (const float4*)(xb + (size_t)(ch + 2) * 128 * Q);
            const float4* gc = (const float4*)(gb + (size_t)(ch + 2) * 128 * Q);
#pragma unroll
            for (int t = 0; t < 8; ++t) {
                const int idx = tid + t * 512;
                xA[t] = xc[idx]; gA[t] = gc[idx];
            }
        }
        __syncthreads();
        {
            float acc[8][4];
#pragma unroll
            for (int i = 0; i < 8; ++i)
#pragma unroll
                for (int j = 0; j < 4; ++j) acc[i][j] = 0.0f;
            for (int k = 0; k < Q; ++k) {
                float a[8];
#pragma unroll
                for (int i = 0; i < 8; ++i) a[i] = sT2[(ty * 8 + i) * 128 + k];
                const float4 bv = ((const float4*)(sZf + k * Q))[tx];
                const float b[4] = {bv.x, bv.y, bv.z, bv.w};
#pragma unroll
                for (int i = 0; i < 8; ++i)
#pragma unroll
                    for (int j = 0; j < 4; ++j) acc[i][j] += a[i] * b[j];
            }
            float* oc = ob + (size_t)(ch + 1) * 128 * Q;
#pragma unroll
            for (int i = 0; i < 8; ++i) {
                float4 v = make_float4(acc[i][0], acc[i][1], acc[i][2], acc[i][3]);
                ((float4*)(oc + (size_t)(ty * 8 + i) * Q))[tx] = v;
            }
        }
    }
}

extern "C" void kernel_launch(void* const* d_in, const int* in_sizes, int n_in,
                              void* d_out, int out_size, void* d_ws, size_t ws_size,
                              hipStream_t stream) {
    const float* X  = (const float*)d_in[0];
    const float* G  = (const float*)d_in[1];
    const float* lr = (const float*)d_in[2];
    float* outp = (float*)d_out;
    float* gram = (float*)d_ws;                       // 16.8 MB
    float* Zg   = gram + (size_t)NBATCH * Q * Q;      // 16.8 MB

    gram_ns_kernel<<<NBATCH, 512, 0, stream>>>(X, G, lr, gram, Zg);
    refine_kernel<<<NBATCH, 512, 0, stream>>>(gram, Zg);
    apply_kernel<<<NBATCH * 2, 512, 0, stream>>>(X, G, lr, Zg, outp);
}

// Round 5
// 865.818 us; speedup vs baseline: 1.0384x; 1.0384x over previous
//
#include <hip/hip_runtime.h>

#define NBATCH 256
#define P 1024
#define Q 128
#define NS_LOOP 10

typedef _Float16 half8 __attribute__((ext_vector_type(8)));
typedef float f32x4 __attribute__((ext_vector_type(4)));
struct Half4 { _Float16 x, y, z, w; };   // 8 bytes

// Swizzled fp16 storage for 128x128 symmetric matrices:
// element (r,c) lives in Half4 slot  r*32 + ((c>>2) ^ (r&15)), component c&3.
__device__ __forceinline__ half8 frag_ld(const Half4* S, int rowbase, int slotbase, int lane) {
    const int r = rowbase + (lane & 15);
    const int g = (lane >> 4);
    const int rx = r & 15;
    const Half4 h1 = S[r * 32 + ((slotbase + g) ^ rx)];
    const Half4 h2 = S[r * 32 + ((slotbase + g + 4) ^ rx)];
    half8 v;
    v[0] = h1.x; v[1] = h1.y; v[2] = h1.z; v[3] = h1.w;
    v[4] = h2.x; v[5] = h2.y; v[6] = h2.z; v[7] = h2.w;
    return v;
}

// C-fragment position, stored TRANSPOSED (ok: iterates symmetric to O(eps)).
__device__ __forceinline__ int cpos(int RB, int CB, int lane) {
    const int r = CB + (lane & 15);
    const int s = (RB >> 2) + (lane >> 4);
    return r * 32 + (s ^ (r & 15));
}

__device__ __forceinline__ f32x4 cread(const Half4* S, int p) {
    const Half4 h = S[p];
    f32x4 v;
    v[0] = (float)h.x; v[1] = (float)h.y; v[2] = (float)h.z; v[3] = (float)h.w;
    return v;
}

__device__ __forceinline__ void cwrite(Half4* S, int p, f32x4 v) {
    Half4 h;
    h.x = (_Float16)v[0]; h.y = (_Float16)v[1]; h.z = (_Float16)v[2]; h.w = (_Float16)v[3];
    S[p] = h;
}

// ---------------------------------------------------------------------------
// Kernel 1 (fused): gram (fp32 VALU) + Newton-Schulz inverse-sqrt (fp16 MFMA).
// __launch_bounds__(512,2): 2 waves/EU -> VGPR cap 256 (r4 had cap 128 ->
// massive scratch spill: FETCH 930MB / WRITE 1.6GB phantom traffic).
// ---------------------------------------------------------------------------
__global__ __launch_bounds__(512, 2) void gram_ns_kernel(
    const float* __restrict__ X, const float* __restrict__ G,
    const float* __restrict__ lrp, float* __restrict__ gram,
    float* __restrict__ Zg)
{
    __shared__ __align__(16) unsigned char pool[98304];
    Half4* sW = (Half4*)pool;
    Half4* sZ = (Half4*)(pool + 32768);
    Half4* sM = (Half4*)(pool + 65536);
    float* sT = (float*)(pool + 65536);   // gram staging aliases sM (16KB)
    __shared__ float sRed[8];

    const int n = blockIdx.x;
    const int tid = threadIdx.x;
    const float lr = *lrp;
    const float* xb = X + (size_t)n * P * Q;
    const float* gb = G + (size_t)n * P * Q;

    // ================= gram phase: acc = temp^T temp =================
    const int ty = tid >> 5, tx = tid & 31;   // 16 x 32 grid, 8x4 tiles
    float acc[8][4];
#pragma unroll
    for (int i = 0; i < 8; ++i)
#pragma unroll
        for (int j = 0; j < 4; ++j) acc[i][j] = 0.0f;

    // temp computed at load time -> only 2 float4/buffer live (was 4)
    float4 tA[2], tB[2];
#pragma unroll
    for (int t = 0; t < 2; ++t) {
        const int idx = tid + t * 512;
        const float4 xv = ((const float4*)xb)[idx];
        const float4 gv = ((const float4*)gb)[idx];
        tA[t] = make_float4(xv.x - lr * gv.x, xv.y - lr * gv.y,
                            xv.z - lr * gv.z, xv.w - lr * gv.w);
    }

    for (int c = 0; c < 32; c += 2) {
        __syncthreads();
#pragma unroll
        for (int t = 0; t < 2; ++t) ((float4*)sT)[tid + t * 512] = tA[t];
        {
            const float4* xc = (const float4*)(xb + (size_t)(c + 1) * 32 * Q);
            const float4* gc = (const float4*)(gb + (size_t)(c + 1) * 32 * Q);
#pragma unroll
            for (int t = 0; t < 2; ++t) {
                const int idx = tid + t * 512;
                const float4 xv = xc[idx];
                const float4 gv = gc[idx];
                tB[t] = make_float4(xv.x - lr * gv.x, xv.y - lr * gv.y,
                                    xv.z - lr * gv.z, xv.w - lr * gv.w);
            }
        }
        __syncthreads();
        for (int p = 0; p < 32; ++p) {
            float a[8];
#pragma unroll
            for (int i = 0; i < 8; ++i) a[i] = sT[p * 128 + ty * 8 + i];
            const float4 bv = ((const float4*)(sT + p * 128))[tx];
            const float b[4] = {bv.x, bv.y, bv.z, bv.w};
#pragma unroll
            for (int i = 0; i < 8; ++i)
#pragma unroll
                for (int j = 0; j < 4; ++j) acc[i][j] += a[i] * b[j];
        }
        __syncthreads();
#pragma unroll
        for (int t = 0; t < 2; ++t) ((float4*)sT)[tid + t * 512] = tB[t];
        if (c + 2 < 32) {
            const float4* xc = (const float4*)(xb + (size_t)(c + 2) * 32 * Q);
            const float4* gc = (const float4*)(gb + (size_t)(c + 2) * 32 * Q);
#pragma unroll
            for (int t = 0; t < 2; ++t) {
                const int idx = tid + t * 512;
                const float4 xv = xc[idx];
                const float4 gv = gc[idx];
                tA[t] = make_float4(xv.x - lr * gv.x, xv.y - lr * gv.y,
                                    xv.z - lr * gv.z, xv.w - lr * gv.w);
            }
        }
        __syncthreads();
        for (int p = 0; p < 32; ++p) {
            float a[8];
#pragma unroll
            for (int i = 0; i < 8; ++i) a[i] = sT[p * 128 + ty * 8 + i];
            const float4 bv = ((const float4*)(sT + p * 128))[tx];
            const float b[4] = {bv.x, bv.y, bv.z, bv.w};
#pragma unroll
            for (int i = 0; i < 8; ++i)
#pragma unroll
                for (int j = 0; j < 4; ++j) acc[i][j] += a[i] * b[j];
        }
    }

    // ---- write raw gram (fp32) for the refiner ----
    float* gmo = gram + (size_t)n * Q * Q;
#pragma unroll
    for (int i = 0; i < 8; ++i) {
        float4 v = make_float4(acc[i][0], acc[i][1], acc[i][2], acc[i][3]);
        ((float4*)(gmo + (size_t)(ty * 8 + i) * Q))[tx] = v;
    }

    // ---- Frobenius norm ----
    float ss = 0.0f;
#pragma unroll
    for (int i = 0; i < 8; ++i)
#pragma unroll
        for (int j = 0; j < 4; ++j) ss += acc[i][j] * acc[i][j];
#pragma unroll
    for (int off = 32; off > 0; off >>= 1) ss += __shfl_down(ss, off, 64);
    if ((tid & 63) == 0) sRed[tid >> 6] = ss;
    __syncthreads();
    float csum = 0.0f;
#pragma unroll
    for (int w = 0; w < 8; ++w) csum += sRed[w];
    const float c = sqrtf(csum);
    const float rc = 1.0f / c;

    // ---- init: W0 = gram/c (fp16), Z0 = 1.5I - 0.5*W0 ----
#pragma unroll
    for (int i = 0; i < 8; ++i) {
        const int row = ty * 8 + i;
        const int slot = row * 32 + (tx ^ (row & 15));
        float wv[4], zv[4];
#pragma unroll
        for (int j = 0; j < 4; ++j) {
            wv[j] = acc[i][j] * rc;
            zv[j] = -0.5f * wv[j] + (((row >> 2) == tx && (row & 3) == j) ? 1.5f : 0.0f);
        }
        Half4 wh, zh;
        wh.x = (_Float16)wv[0]; wh.y = (_Float16)wv[1]; wh.z = (_Float16)wv[2]; wh.w = (_Float16)wv[3];
        zh.x = (_Float16)zv[0]; zh.y = (_Float16)zv[1]; zh.z = (_Float16)zv[2]; zh.w = (_Float16)zv[3];
        sW[slot] = wh;
        sZ[slot] = zh;
    }
    __syncthreads();

    // ================= NS phase (fp16 MFMA) =================
    const int lane = tid & 63;
    const int wid = tid >> 6;
    const int wr = wid >> 2;
    const int wc = wid & 3;
    const f32x4 zero4 = {0.0f, 0.0f, 0.0f, 0.0f};

    for (int it = 0; it < NS_LOOP; ++it) {
        // --- GEMM1: M = 1.5W - 0.5*(W*W) ---
        f32x4 a1[4][2];
#pragma unroll
        for (int fi = 0; fi < 4; ++fi)
#pragma unroll
            for (int fj = 0; fj < 2; ++fj) a1[fi][fj] = zero4;
#pragma unroll
        for (int kb = 0; kb < 4; ++kb) {
            half8 af[4], bf[2];
#pragma unroll
            for (int fi = 0; fi < 4; ++fi) af[fi] = frag_ld(sW, wr * 64 + fi * 16, kb * 8, lane);
#pragma unroll
            for (int fj = 0; fj < 2; ++fj) bf[fj] = frag_ld(sW, wc * 32 + fj * 16, kb * 8, lane);
#pragma unroll
            for (int fi = 0; fi < 4; ++fi)
#pragma unroll
                for (int fj = 0; fj < 2; ++fj)
                    a1[fi][fj] = __builtin_amdgcn_mfma_f32_16x16x32_f16(af[fi], bf[fj], a1[fi][fj], 0, 0, 0);
        }
#pragma unroll
        for (int fi = 0; fi < 4; ++fi)
#pragma unroll
            for (int fj = 0; fj < 2; ++fj) {
                const int p = cpos(wr * 64 + fi * 16, wc * 32 + fj * 16, lane);
                cwrite(sM, p, 1.5f * cread(sW, p) - 0.5f * a1[fi][fj]);
            }
        __syncthreads();

        // --- GEMM2: Wnew = 1.5M - 0.5*(M*W) ---
        f32x4 a2[4][2];
#pragma unroll
        for (int fi = 0; fi < 4; ++fi)
#pragma unroll
            for (int fj = 0; fj < 2; ++fj) a2[fi][fj] = zero4;
#pragma unroll
        for (int kb = 0; kb < 4; ++kb) {
            half8 af[4], bf[2];
#pragma unroll
            for (int fi = 0; fi < 4; ++fi) af[fi] = frag_ld(sM, wr * 64 + fi * 16, kb * 8, lane);
#pragma unroll
            for (int fj = 0; fj < 2; ++fj) bf[fj] = frag_ld(sW, wc * 32 + fj * 16, kb * 8, lane);
#pragma unroll
            for (int fi = 0; fi < 4; ++fi)
#pragma unroll
                for (int fj = 0; fj < 2; ++fj)
                    a2[fi][fj] = __builtin_amdgcn_mfma_f32_16x16x32_f16(af[fi], bf[fj], a2[fi][fj], 0, 0, 0);
        }
        f32x4 wn[4][2];
#pragma unroll
        for (int fi = 0; fi < 4; ++fi)
#pragma unroll
            for (int fj = 0; fj < 2; ++fj) {
                const int p = cpos(wr * 64 + fi * 16, wc * 32 + fj * 16, lane);
                wn[fi][fj] = 1.5f * cread(sM, p) - 0.5f * a2[fi][fj];
            }
        __syncthreads();
#pragma unroll
        for (int fi = 0; fi < 4; ++fi)
#pragma unroll
            for (int fj = 0; fj < 2; ++fj)
                cwrite(sW, cpos(wr * 64 + fi * 16, wc * 32 + fj * 16, lane), wn[fi][fj]);
        __syncthreads();

        // --- GEMM3: Znew = 1.5Z - 0.5*(Wnew*Z) ---
        f32x4 a3[4][2];
#pragma unroll
        for (int fi = 0; fi < 4; ++fi)
#pragma unroll
            for (int fj = 0; fj < 2; ++fj) a3[fi][fj] = zero4;
#pragma unroll
        for (int kb = 0; kb < 4; ++kb) {
            half8 af[4], bf[2];
#pragma unroll
            for (int fi = 0; fi < 4; ++fi) af[fi] = frag_ld(sW, wr * 64 + fi * 16, kb * 8, lane);
#pragma unroll
            for (int fj = 0; fj < 2; ++fj) bf[fj] = frag_ld(sZ, wc * 32 + fj * 16, kb * 8, lane);
#pragma unroll
            for (int fi = 0; fi < 4; ++fi)
#pragma unroll
                for (int fj = 0; fj < 2; ++fj)
                    a3[fi][fj] = __builtin_amdgcn_mfma_f32_16x16x32_f16(af[fi], bf[fj], a3[fi][fj], 0, 0, 0);
        }
        f32x4 zn[4][2];
#pragma unroll
        for (int fi = 0; fi < 4; ++fi)
#pragma unroll
            for (int fj = 0; fj < 2; ++fj) {
                const int p = cpos(wr * 64 + fi * 16, wc * 32 + fj * 16, lane);
                zn[fi][fj] = 1.5f * cread(sZ, p) - 0.5f * a3[fi][fj];
            }
        __syncthreads();
#pragma unroll
        for (int fi = 0; fi < 4; ++fi)
#pragma unroll
            for (int fj = 0; fj < 2; ++fj)
                cwrite(sZ, cpos(wr * 64 + fi * 16, wc * 32 + fj * 16, lane), zn[fi][fj]);
        __syncthreads();
    }

    // ---- Zg = Z / sqrt(c) ----
    const float rs = 1.0f / sqrtf(c);
    float* zo = Zg + (size_t)n * Q * Q;
#pragma unroll
    for (int t = 0; t < 8; ++t) {
        const int idx = tid + t * 512;
        const int row = idx >> 5, c4 = idx & 31;
        const Half4 h = sZ[row * 32 + (c4 ^ (row & 15))];
        float4 o;
        o.x = (float)h.x * rs; o.y = (float)h.y * rs;
        o.z = (float)h.z * rs; o.w = (float)h.w * rs;
        ((float4*)(zo + row * Q))[c4] = o;
    }
}

// ---------------------------------------------------------------------------
// Kernel 1b: one fp32 Newton-Schulz refinement step (quadratic cleanup).
//   Z = 1.5*Y - 0.5 * Y*(S*(Y*Y)), exact operand order (no commuting).
// ---------------------------------------------------------------------------
__global__ __launch_bounds__(512, 2) void refine_kernel(
    const float* __restrict__ gram, float* __restrict__ Zg)
{
    __shared__ float sY[Q * Q];
    __shared__ float sU[Q * Q];
    __shared__ float sR[32 * Q];
    const int n = blockIdx.x;
    const int tid = threadIdx.x;
    const float* gm = gram + (size_t)n * Q * Q;
    float* zg = Zg + (size_t)n * Q * Q;
    const int ty = tid >> 5, tx = tid & 31;

#pragma unroll
    for (int t = 0; t < 8; ++t) {
        const int idx = tid + t * 512;
        ((float4*)sY)[idx] = ((const float4*)zg)[idx];
    }
    __syncthreads();

    // U = Y*Y
    {
        float acc[8][4];
#pragma unroll
        for (int i = 0; i < 8; ++i)
#pragma unroll
            for (int j = 0; j < 4; ++j) acc[i][j] = 0.0f;
        for (int k = 0; k < Q; ++k) {
            float a[8];
#pragma unroll
            for (int i = 0; i < 8; ++i) a[i] = sY[(ty * 8 + i) * Q + k];
            const float4 bv = ((const float4*)(sY + k * Q))[tx];
            const float b[4] = {bv.x, bv.y, bv.z, bv.w};
#pragma unroll
            for (int i = 0; i < 8; ++i)
#pragma unroll
                for (int j = 0; j < 4; ++j) acc[i][j] += a[i] * b[j];
        }
#pragma unroll
        for (int i = 0; i < 8; ++i) {
            float4 v = make_float4(acc[i][0], acc[i][1], acc[i][2], acc[i][3]);
            ((float4*)(sU + (ty * 8 + i) * Q))[tx] = v;
        }
    }
    __syncthreads();

    for (int ch = 0; ch < 4; ++ch) {
        const int r0 = ch * 32 + ty * 2;
        float acc[2][4];
#pragma unroll
        for (int i = 0; i < 2; ++i)
#pragma unroll
            for (int j = 0; j < 4; ++j) acc[i][j] = 0.0f;
        for (int k = 0; k < Q; ++k) {
            const float a0 = sY[(r0 + 0) * Q + k];
            const float a1 = sY[(r0 + 1) * Q + k];
            const float4 bv = ((const float4*)(gm + (size_t)k * Q))[tx];
            acc[0][0] += a0 * bv.x; acc[0][1] += a0 * bv.y;
            acc[0][2] += a0 * bv.z; acc[0][3] += a0 * bv.w;
            acc[1][0] += a1 * bv.x; acc[1][1] += a1 * bv.y;
            acc[1][2] += a1 * bv.z; acc[1][3] += a1 * bv.w;
        }
        __syncthreads();
#pragma unroll
        for (int i = 0; i < 2; ++i) {
            float4 v = make_float4(acc[i][0], acc[i][1], acc[i][2], acc[i][3]);
            ((float4*)(sR + (ty * 2 + i) * Q))[tx] = v;
        }
        __syncthreads();

        float acc2[2][4];
#pragma unroll
        for (int i = 0; i < 2; ++i)
#pragma unroll
            for (int j = 0; j < 4; ++j) acc2[i][j] = 0.0f;
        for (int k = 0; k < Q; ++k) {
            const float a0 = sR[(ty * 2 + 0) * Q + k];
            const float a1 = sR[(ty * 2 + 1) * Q + k];
            const float4 bv = ((const float4*)(sU + k * Q))[tx];
            acc2[0][0] += a0 * bv.x; acc2[0][1] += a0 * bv.y;
            acc2[0][2] += a0 * bv.z; acc2[0][3] += a0 * bv.w;
            acc2[1][0] += a1 * bv.x; acc2[1][1] += a1 * bv.y;
            acc2[1][2] += a1 * bv.z; acc2[1][3] += a1 * bv.w;
        }
#pragma unroll
        for (int i = 0; i < 2; ++i) {
            const float4 yv = ((const float4*)(sY + (r0 + i) * Q))[tx];
            float4 o;
            o.x = 1.5f * yv.x - 0.5f * acc2[i][0];
            o.y = 1.5f * yv.y - 0.5f * acc2[i][1];
            o.z = 1.5f * yv.z - 0.5f * acc2[i][2];
            o.w = 1.5f * yv.w - 0.5f * acc2[i][3];
            ((float4*)(zg + (size_t)(r0 + i) * Q))[tx] = o;
        }
    }
}

// ---------------------------------------------------------------------------
// Kernel 2: out[n] = temp[n] @ Zg[n]. 2 blocks/batch, 512 threads.
// temp computed at load time: staging = 16 float4 (was 32 -> spilled at cap 128).
// ---------------------------------------------------------------------------
__global__ __launch_bounds__(512, 2) void apply_kernel(
    const float* __restrict__ X, const float* __restrict__ G,
    const float* __restrict__ lrp, const float* __restrict__ Zg,
    float* __restrict__ out)
{
    __shared__ float sZf[Q * Q];
    __shared__ float sT2[128 * Q];

    const int n = blockIdx.x >> 1;
    const int rb = (blockIdx.x & 1) * 512;
    const int tid = threadIdx.x;
    const float lr = *lrp;
    const float* xb = X + (size_t)n * P * Q + (size_t)rb * Q;
    const float* gb = G + (size_t)n * P * Q + (size_t)rb * Q;
    float* ob = out + (size_t)n * P * Q + (size_t)rb * Q;

#pragma unroll
    for (int t = 0; t < 8; ++t) {
        const int idx = tid + t * 512;
        ((float4*)sZf)[idx] = ((const float4*)(Zg + (size_t)n * Q * Q))[idx];
    }

    const int ty = tid >> 5, tx = tid & 31;
    float4 tA[8], tB[8];
#pragma unroll
    for (int t = 0; t < 8; ++t) {
        const int idx = tid + t * 512;
        const float4 xv = ((const float4*)xb)[idx];
        const float4 gv = ((const float4*)gb)[idx];
        tA[t] = make_float4(xv.x - lr * gv.x, xv.y - lr * gv.y,
                            xv.z - lr * gv.z, xv.w - lr * gv.w);
    }

    for (int ch = 0; ch < 4; ch += 2) {
        __syncthreads();
#pragma unroll
        for (int t = 0; t < 8; ++t) ((float4*)sT2)[tid + t * 512] = tA[t];
        {
            const float4* xc = (const float4*)(xb + (size_t)(ch + 1) * 128 * Q);
            const float4* gc = (const float4*)(gb + (size_t)(ch + 1) * 128 * Q);
#pragma unroll
            for (int t = 0; t < 8; ++t) {
                const int idx = tid + t * 512;
                const float4 xv = xc[idx];
                const float4 gv = gc[idx];
                tB[t] = make_float4(xv.x - lr * gv.x, xv.y - lr * gv.y,
                                    xv.z - lr * gv.z, xv.w - lr * gv.w);
            }
        }
        __syncthreads();
        {
            float acc[8][4];
#pragma unroll
            for (int i = 0; i < 8; ++i)
#pragma unroll
                for (int j = 0; j < 4; ++j) acc[i][j] = 0.0f;
            for (int k = 0; k < Q; ++k) {
                float a[8];
#pragma unroll
                for (int i = 0; i < 8; ++i) a[i] = sT2[(ty * 8 + i) * 128 + k];
                const float4 bv = ((const float4*)(sZf + k * Q))[tx];
                const float b[4] = {bv.x, bv.y, bv.z, bv.w};
#pragma unroll
                for (int i = 0; i < 8; ++i)
#pragma unroll
                    for (int j = 0; j < 4; ++j) acc[i][j] += a[i] * b[j];
            }
            float* oc = ob + (size_t)ch * 128 * Q;
#pragma unroll
            for (int i = 0; i < 8; ++i) {
                float4 v = make_float4(acc[i][0], acc[i][1], acc[i][2], acc[i][3]);
                ((float4*)(oc + (size_t)(ty * 8 + i) * Q))[tx] = v;
            }
        }
        __syncthreads();
#pragma unroll
        for (int t = 0; t < 8; ++t) ((float4*)sT2)[tid + t * 512] = tB[t];
        if (ch + 2 < 4) {
            const float4* xc = (const float4*)(xb + (size_t)(ch + 2) * 128 * Q);
            const float4* gc = (const float4*)(gb + (size_t)(ch + 2) * 128 * Q);
#pragma unroll
            for (int t = 0; t < 8; ++t) {
                const int idx = tid + t * 512;
                const float4 xv = xc[idx];
                const float4 gv = gc[idx];
                tA[t] = make_float4(xv.x - lr * gv.x, xv.y - lr * gv.y,
                                    xv.z - lr * gv.z, xv.w - lr * gv.w);
            }
        }
        __syncthreads();
        {
            float acc[8][4];
#pragma unroll
            for (int i = 0; i < 8; ++i)
#pragma unroll
                for (int j = 0; j < 4; ++j) acc[i][j] = 0.0f;
            for (int k = 0; k < Q; ++k) {
                float a[8];
#pragma unroll
                for (int i = 0; i < 8; ++i) a[i] = sT2[(ty * 8 + i) * 128 + k];
                const float4 bv = ((const float4*)(sZf + k * Q))[tx];
                const float b[4] = {bv.x, bv.y, bv.z, bv.w};
#pragma unroll
                for (int i = 0; i < 8; ++i)
#pragma unroll
                    for (int j = 0; j < 4; ++j) acc[i][j] += a[i] * b[j];
            }
            float* oc = ob + (size_t)(ch + 1) * 128 * Q;
#pragma unroll
            for (int i = 0; i < 8; ++i) {
                float4 v = make_float4(acc[i][0], acc[i][1], acc[i][2], acc[i][3]);
                ((float4*)(oc + (size_t)(ty * 8 + i) * Q))[tx] = v;
            }
        }
    }
}

extern "C" void kernel_launch(void* const* d_in, const int* in_sizes, int n_in,
                              void* d_out, int out_size, void* d_ws, size_t ws_size,
                              hipStream_t stream) {
    const float* X  = (const float*)d_in[0];
    const float* G  = (const float*)d_in[1];
    const float* lr = (const float*)d_in[2];
    float* outp = (float*)d_out;
    float* gram = (float*)d_ws;                       // 16.8 MB
    float* Zg   = gram + (size_t)NBATCH * Q * Q;      // 16.8 MB

    gram_ns_kernel<<<NBATCH, 512, 0, stream>>>(X, G, lr, gram, Zg);
    refine_kernel<<<NBATCH, 512, 0, stream>>>(gram, Zg);
    apply_kernel<<<NBATCH * 2, 512, 0, stream>>>(X, G, lr, Zg, outp);
}